// Round 4
// baseline (156.671 us; speedup 1.0000x reference)
//
#include <hip/hip_runtime.h>
#include <math.h>

#define N_NODES 20000
#define N_EDGES 160000
#define EPSB 1e-5f
#define SLOPE 0.01f

typedef __attribute__((ext_vector_type(8))) short short8;   // 8 bf16 (4 VGPRs)
typedef __attribute__((ext_vector_type(4))) float f32x4;    // MFMA C/D

// ---- workspace layout (float element offsets) ----
// zeroed region (one 411 KB memset):
#define OFF_ND     0        // float4[20000]: {x, degf, A=sum dinv_s*x_s, C=sum dinv_s}
#define OFF_B      80000    // float[20000]:  sum q2_s per dst (edge pass 2)
#define OFF_V      100000   // float[1024]
#define OFF_U      101024   // float[1024]
#define OFF_R      102048   // float[256]
#define OFF_RU     102304   // float[256]
#define OFF_S      102560   // float[256]
#define OFF_ZEND   102816
// non-zeroed:
#define OFF_BFRAG  102816   // bf16[8 ct][8 ks][64 lane][8 j] = 32768 halves

#define T_STRIDE 264   // halves; 528 B rows keep 16B alignment for ds_read_b128

__device__ __forceinline__ unsigned short f2bf(float f) {
    unsigned u = __float_as_uint(f);
    return (unsigned short)((u + 0x7FFFu + ((u >> 16) & 1u)) >> 16);   // RNE
}

// E1: blocks [0,625) degree histogram (float, into nd.y); [625,881) v,u = (W1,b1)@W2;
// [881,897) bfrag pack; [897,976) copy x into nd.x (disjoint dwords from atomics).
__global__ void E1_deg_v_bf(const int* __restrict__ dst, float* __restrict__ ndf,
                            const float* __restrict__ x,
                            const float* __restrict__ W1, const float* __restrict__ b1,
                            const float* __restrict__ W2, const float* __restrict__ lW2,
                            float* __restrict__ v, float* __restrict__ u,
                            unsigned short* __restrict__ bfrag) {
    int b = blockIdx.x;
    if (b < 625) {
        int e = b * 256 + threadIdx.x;      // 625*256 = 160000 exact
        unsafeAtomicAdd(&ndf[4 * dst[e] + 1], 1.0f);   // degf (exact to 2^24)
    } else if (b < 881) {
        int bb = b - 625;                   // 0..255
        int k  = (bb & 3) * 256 + threadIdx.x;
        int c0 = (bb >> 2) * 32;            // 64 chunks of 32
        float av = 0.f, au = 0.f;
        for (int c = c0; c < c0 + 32; ++c) {
            float w = W2[c * 1024 + k];     // coalesced
            av = fmaf(W1[c], w, av);
            au = fmaf(b1[c], w, au);
        }
        unsafeAtomicAdd(&v[k], av);
        unsafeAtomicAdd(&u[k], au);
    } else if (b < 897) {
        int i = (b - 881) * 256 + threadIdx.x;    // 0..4095 = (ct,ks,lane)
        int ct = i >> 9, ks = (i >> 6) & 7, lane = i & 63;
        int n  = ct * 16 + (lane & 15);
        int kb = ks * 32 + (lane >> 4) * 8;
        union { unsigned short u8[8]; short8 v8; } pk;
#pragma unroll
        for (int j = 0; j < 8; ++j)
            pk.u8[j] = (n < 124) ? f2bf(lW2[(kb + j) * 124 + n]) : (unsigned short)0;
        ((short8*)bfrag)[i] = pk.v8;
    } else {
        int n = (b - 897) * 256 + threadIdx.x;
        if (n < N_NODES) ndf[4 * n] = x[n];        // nd.x; disjoint from degf atomics
    }
}

// E2: blocks [0,625) edges pass 1 — ONE 8B scattered gather ({x,degf}[sn]) + two
// atomics into the SAME 16B line nd[d].{z,w}; [625,657) fold BN+Linear1 into r/ru/s.
__global__ void E2_edges1_rs(const int* __restrict__ src, const int* __restrict__ dst,
                             float* __restrict__ ndf,
                             const float* __restrict__ v, const float* __restrict__ u,
                             const float* __restrict__ gamma, const float* __restrict__ beta,
                             const float* __restrict__ mean, const float* __restrict__ var,
                             const float* __restrict__ b2, const float* __restrict__ lW1,
                             const float* __restrict__ lb1,
                             float* __restrict__ r, float* __restrict__ ru,
                             float* __restrict__ s) {
    int b = blockIdx.x;
    if (b < 625) {
        int e = b * 256 + threadIdx.x;
        int sn = src[e], d = dst[e];
        float2 sv = ((const float2*)ndf)[2 * sn];        // {x, degf} — one gather
        float dinv = rsqrtf(sv.y + 1.0f);                // src-side norm only
        unsafeAtomicAdd(&ndf[4 * d + 2], dinv * sv.x);   // A — same 16B line as C
        unsafeAtomicAdd(&ndf[4 * d + 3], dinv);          // C
    } else {
        int bb = b - 625, m = threadIdx.x, k0 = bb * 32;
        float ar = 0.f, aru = 0.f, as = 0.f;
        for (int k = k0; k < k0 + 32; ++k) {
            float g = gamma[k] * rsqrtf(var[k] + EPSB);
            float w = lW1[k * 256 + m];
            ar  = fmaf(v[k] * g, w, ar);
            aru = fmaf(u[k] * g, w, aru);
            as  = fmaf(fmaf(b2[k] - mean[k], g, beta[k]), w, as);
        }
        if (bb == 0) as += lb1[m];
        unsafeAtomicAdd(&r[m], ar);
        unsafeAtomicAdd(&ru[m], aru);
        unsafeAtomicAdd(&s[m], as);
    }
}

// E3: edges pass 2 — ONE 16B scattered gather (nd[sn]) + one atomic per edge.
// q2[s] = dinv^2 * (A + dinv*x), dinv = rsqrt(degf+1).
__global__ void E3_edges2(const int* __restrict__ src, const int* __restrict__ dst,
                          const float4* __restrict__ nd4, float* __restrict__ B) {
    int e = blockIdx.x * 256 + threadIdx.x;
    int sn = src[e], d = dst[e];
    float4 nv = nd4[sn];                     // {x, degf, A, C} — one 16B gather
    float dinv = rsqrtf(nv.y + 1.0f);
    float q2 = dinv * dinv * (nv.z + dinv * nv.x);
    unsafeAtomicAdd(&B[d], q2);
}

// F: MFMA final stage. Block = 256 thr (4 waves), 2 node-tiles of 16 nodes.
// a = dinv*(B + q2[n]); cnf = dinv*(C + dinv); all from nd[n]. Phase A:
// T[16 node][256 m] = leaky(a*r + cnf*ru + s) bf16 in LDS. Phase B: wave w owns
// cols [32w,32w+32): 8 ds_read_b128 A-frags x 2 preloaded B-tiles ->
// 16 mfma_f32_16x16x32_bf16. Fused log_softmax + lb2.
__global__ __launch_bounds__(256, 2) void F_final(
    const float4* __restrict__ nd4, const float* __restrict__ B,
    const float* __restrict__ r, const float* __restrict__ ru,
    const float* __restrict__ s,
    const short8* __restrict__ bfrag, const float* __restrict__ lb2,
    float* __restrict__ out) {
    __shared__ unsigned short tsh[16 * T_STRIDE];   // 8448 B
    __shared__ float a_sh[16], cn_sh[16];
    __shared__ float logits[16 * 132];              // 8448 B
    int tid  = threadIdx.x;
    int lane = tid & 63;
    int wave = __builtin_amdgcn_readfirstlane(tid >> 6);   // 0..3
    int row  = lane & 15, quad = lane >> 4;

    // preload B-fragments for this wave's two 16-col tiles (reused across tiles)
    short8 bf0[8], bf1[8];
#pragma unroll
    for (int ks = 0; ks < 8; ++ks) {
        bf0[ks] = bfrag[((wave * 2 + 0) * 8 + ks) * 64 + lane];
        bf1[ks] = bfrag[((wave * 2 + 1) * 8 + ks) * 64 + lane];
    }
    float cr = r[tid], cu = ru[tid], cs = s[tid];   // m = tid, constant across tiles

    for (int it = 0; it < 2; ++it) {
        int node0 = (blockIdx.x * 2 + it) * 16;     // 1250 tiles = 625 blocks x 2, exact
        if (tid < 16) {
            int n = node0 + tid;
            float4 nv = nd4[n];
            float dinv = rsqrtf(nv.y + 1.0f);
            float q2n  = dinv * dinv * (nv.z + dinv * nv.x);   // dinv * agg1_full
            a_sh[tid]  = dinv * (B[n] + q2n);
            cn_sh[tid] = dinv * (nv.w + dinv);
        }
        __syncthreads();                            // (0) a_sh ready; prev tsh readers done

        // Phase A: T tile, bf16
#pragma unroll
        for (int n = 0; n < 16; ++n) {
            float t = fmaf(cn_sh[n], cu, fmaf(a_sh[n], cr, cs));
            t = fmaf(SLOPE, fminf(t, 0.f), fmaxf(t, 0.f));
            tsh[n * T_STRIDE + tid] = f2bf(t);
        }
        __syncthreads();                            // (1)

        // Phase B: MFMA — wave w owns cols [32w, 32w+32)
        f32x4 acc0 = {0.f, 0.f, 0.f, 0.f}, acc1 = {0.f, 0.f, 0.f, 0.f};
        const unsigned short* tb = &tsh[row * T_STRIDE + quad * 8];
#pragma unroll
        for (int ks = 0; ks < 8; ++ks) {
            short8 af = *(const short8*)(tb + ks * 32);   // ds_read_b128, 16B aligned
            acc0 = __builtin_amdgcn_mfma_f32_16x16x32_bf16(af, bf0[ks], acc0, 0, 0, 0);
            acc1 = __builtin_amdgcn_mfma_f32_16x16x32_bf16(af, bf1[ks], acc1, 0, 0, 0);
        }
        int colbase = wave * 32;
#pragma unroll
        for (int rg = 0; rg < 4; ++rg) {
            int rw = quad * 4 + rg;                 // D: row=(lane>>4)*4+reg, col=lane&15
            logits[rw * 132 + colbase + row]      = acc0[rg];
            logits[rw * 132 + colbase + 16 + row] = acc1[rg];
        }
        __syncthreads();                            // (2)

        // log_softmax: 16 threads per node, 8 cols each (last sub: 4 valid)
        int nd = tid >> 4, sub = tid & 15, c0 = sub * 8;
        int jend = 124 - c0; if (jend > 8) jend = 8;
        float vbuf[8];
        const float* lrow = &logits[nd * 132 + c0];
        float mx = -1e30f;
        for (int j = 0; j < jend; ++j) {
            vbuf[j] = lrow[j] + lb2[c0 + j];
            mx = fmaxf(mx, vbuf[j]);
        }
        mx = fmaxf(mx, __shfl_xor(mx, 1, 16));
        mx = fmaxf(mx, __shfl_xor(mx, 2, 16));
        mx = fmaxf(mx, __shfl_xor(mx, 4, 16));
        mx = fmaxf(mx, __shfl_xor(mx, 8, 16));
        float sm = 0.f;
        for (int j = 0; j < jend; ++j) sm += __expf(vbuf[j] - mx);
        sm += __shfl_xor(sm, 1, 16);
        sm += __shfl_xor(sm, 2, 16);
        sm += __shfl_xor(sm, 4, 16);
        sm += __shfl_xor(sm, 8, 16);
        float lz = mx + __logf(sm);
        float* orow = out + (node0 + nd) * 124 + c0;
        for (int j = 0; j < jend; ++j) orow[j] = vbuf[j] - lz;
    }
}

extern "C" void kernel_launch(void* const* d_in, const int* in_sizes, int n_in,
                              void* d_out, int out_size, void* d_ws, size_t ws_size,
                              hipStream_t stream) {
    const float* x     = (const float*)d_in[0];
    const int*   ei    = (const int*)d_in[1];
    const int*   src   = ei;
    const int*   dst   = ei + N_EDGES;
    const float* W1    = (const float*)d_in[2];
    const float* b1    = (const float*)d_in[3];
    const float* W2    = (const float*)d_in[4];
    const float* b2    = (const float*)d_in[5];
    const float* gamma = (const float*)d_in[6];
    const float* beta  = (const float*)d_in[7];
    const float* rmean = (const float*)d_in[8];
    const float* rvar  = (const float*)d_in[9];
    const float* lW1   = (const float*)d_in[10];
    const float* lb1   = (const float*)d_in[11];
    const float* lW2   = (const float*)d_in[12];
    const float* lb2   = (const float*)d_in[13];
    float* out = (float*)d_out;
    float* ws  = (float*)d_ws;

    float* ndf = ws + OFF_ND;               // float4[20000] viewed as float*
    float* B   = ws + OFF_B;
    float* v   = ws + OFF_V;
    float* u   = ws + OFF_U;
    float* r   = ws + OFF_R;
    float* ru  = ws + OFF_RU;
    float* s   = ws + OFF_S;
    unsigned short* bfrag = (unsigned short*)(ws + OFF_BFRAG);

    // one compact memset over all atomic-accumulation targets (411 KB)
    hipMemsetAsync(ws, 0, OFF_ZEND * sizeof(float), stream);

    E1_deg_v_bf<<<625 + 256 + 16 + 79, 256, 0, stream>>>(dst, ndf, x, W1, b1, W2, lW2,
                                                         v, u, bfrag);
    E2_edges1_rs<<<625 + 32, 256, 0, stream>>>(src, dst, ndf, v, u, gamma, beta,
                                               rmean, rvar, b2, lW1, lb1, r, ru, s);
    E3_edges2<<<625, 256, 0, stream>>>(src, dst, (const float4*)ndf, B);
    F_final<<<625, 256, 0, stream>>>((const float4*)ndf, B, r, ru, s,
                                     (const short8*)bfrag, lb2, out);
}

// Round 5
// 150.089 us; speedup vs baseline: 1.0439x; 1.0439x over previous
//
#include <hip/hip_runtime.h>
#include <math.h>

#define N_NODES 20000
#define N_EDGES 160000
#define EPSB 1e-5f
#define SLOPE 0.01f

typedef __attribute__((ext_vector_type(8))) short short8;   // 8 bf16 (4 VGPRs)
typedef __attribute__((ext_vector_type(4))) float f32x4;    // MFMA C/D

// ---- workspace layout (float element offsets) ----
// zeroed region (one 331 KB memset):
#define OFF_DEG    0        // int[20000]
#define OFF_ACC2   20000    // float2[20000]: {A = sum dinv_s*x_s, C = sum dinv_s} per dst
#define OFF_B      60000    // float[20000]:  sum q2_s per dst (edge pass 2)
#define OFF_V      80000    // float[1024]
#define OFF_U      81024    // float[1024]
#define OFF_R      82048    // float[256]
#define OFF_RU     82304    // float[256]
#define OFF_S      82560    // float[256]
#define OFF_ZEND   82816
// non-zeroed:
#define OFF_Q1     82816    // float2[20000]: {dinv*x, dinv}
#define OFF_BFRAG  122816   // bf16[8 ct][8 ks][64 lane][8 j] = 32768 halves

#define T_STRIDE 264   // halves; 528 B rows keep 16B alignment for ds_read_b128
#define EQ 40000       // edge quads (160000/4)
#define EQB 157        // ceil(40000/256) blocks for edge-quad passes

__device__ __forceinline__ unsigned short f2bf(float f) {
    unsigned u = __float_as_uint(f);
    return (unsigned short)((u + 0x7FFFu + ((u >> 16) & 1u)) >> 16);   // RNE
}

// E1: blocks [0,157) degree histogram, 4 edges/thread (int4 index load, 4 atomics);
// [157,413) v,u = (W1,b1)@W2; [413,429) bfrag pack.
__global__ void E1_deg_v_bf(const int* __restrict__ dst, int* __restrict__ deg,
                            const float* __restrict__ W1, const float* __restrict__ b1,
                            const float* __restrict__ W2, const float* __restrict__ lW2,
                            float* __restrict__ v, float* __restrict__ u,
                            unsigned short* __restrict__ bfrag) {
    int b = blockIdx.x;
    if (b < EQB) {
        int t = b * 256 + threadIdx.x;
        if (t < EQ) {
            int4 d4 = ((const int4*)dst)[t];      // one coalesced 16B load
            atomicAdd(&deg[d4.x], 1);
            atomicAdd(&deg[d4.y], 1);
            atomicAdd(&deg[d4.z], 1);
            atomicAdd(&deg[d4.w], 1);
        }
    } else if (b < EQB + 256) {
        int bb = b - EQB;                   // 0..255
        int k  = (bb & 3) * 256 + threadIdx.x;
        int c0 = (bb >> 2) * 32;            // 64 chunks of 32
        float av = 0.f, au = 0.f;
        for (int c = c0; c < c0 + 32; ++c) {
            float w = W2[c * 1024 + k];     // coalesced
            av = fmaf(W1[c], w, av);
            au = fmaf(b1[c], w, au);
        }
        unsafeAtomicAdd(&v[k], av);
        unsafeAtomicAdd(&u[k], au);
    } else {
        int i = (b - (EQB + 256)) * 256 + threadIdx.x;    // 0..4095 = (ct,ks,lane)
        int ct = i >> 9, ks = (i >> 6) & 7, lane = i & 63;
        int n  = ct * 16 + (lane & 15);
        int kb = ks * 32 + (lane >> 4) * 8;
        union { unsigned short u8[8]; short8 v8; } pk;
#pragma unroll
        for (int j = 0; j < 8; ++j)
            pk.u8[j] = (n < 124) ? f2bf(lW2[(kb + j) * 124 + n]) : (unsigned short)0;
        ((short8*)bfrag)[i] = pk.v8;
    }
}

// E2: blocks [0,157) edges pass 1, 4 edges/thread — 8 independent gathers in flight,
// 8 fire-and-forget adjacent-line atomics; [157,189) fold BN+Linear1 into r/ru/s;
// [189,268) q1[n] = {dinv*x, dinv}.
__global__ void E2_edges1_rs_q1(const int* __restrict__ src, const int* __restrict__ dst,
                                const int* __restrict__ deg, const float* __restrict__ x,
                                float* __restrict__ acc2, float2* __restrict__ q1,
                                const float* __restrict__ v, const float* __restrict__ u,
                                const float* __restrict__ gamma, const float* __restrict__ beta,
                                const float* __restrict__ mean, const float* __restrict__ var,
                                const float* __restrict__ b2, const float* __restrict__ lW1,
                                const float* __restrict__ lb1,
                                float* __restrict__ r, float* __restrict__ ru,
                                float* __restrict__ s) {
    int b = blockIdx.x;
    if (b < EQB) {
        int t = b * 256 + threadIdx.x;
        if (t < EQ) {
            int4 s4 = ((const int4*)src)[t];
            int4 d4 = ((const int4*)dst)[t];
            // 8 independent scattered loads (compiler issues them back-to-back)
            int   g0 = deg[s4.x], g1 = deg[s4.y], g2 = deg[s4.z], g3 = deg[s4.w];
            float x0 = x[s4.x],   x1 = x[s4.y],   x2 = x[s4.z],   x3 = x[s4.w];
            float i0 = rsqrtf((float)(g0 + 1)), i1 = rsqrtf((float)(g1 + 1));
            float i2 = rsqrtf((float)(g2 + 1)), i3 = rsqrtf((float)(g3 + 1));
            unsafeAtomicAdd(&acc2[2 * d4.x],     i0 * x0);
            unsafeAtomicAdd(&acc2[2 * d4.x + 1], i0);
            unsafeAtomicAdd(&acc2[2 * d4.y],     i1 * x1);
            unsafeAtomicAdd(&acc2[2 * d4.y + 1], i1);
            unsafeAtomicAdd(&acc2[2 * d4.z],     i2 * x2);
            unsafeAtomicAdd(&acc2[2 * d4.z + 1], i2);
            unsafeAtomicAdd(&acc2[2 * d4.w],     i3 * x3);
            unsafeAtomicAdd(&acc2[2 * d4.w + 1], i3);
        }
    } else if (b < EQB + 32) {
        int bb = b - EQB, m = threadIdx.x, k0 = bb * 32;
        float ar = 0.f, aru = 0.f, as = 0.f;
        for (int k = k0; k < k0 + 32; ++k) {
            float g = gamma[k] * rsqrtf(var[k] + EPSB);
            float w = lW1[k * 256 + m];
            ar  = fmaf(v[k] * g, w, ar);
            aru = fmaf(u[k] * g, w, aru);
            as  = fmaf(fmaf(b2[k] - mean[k], g, beta[k]), w, as);
        }
        if (bb == 0) as += lb1[m];
        unsafeAtomicAdd(&r[m], ar);
        unsafeAtomicAdd(&ru[m], aru);
        unsafeAtomicAdd(&s[m], as);
    } else {
        int n = (b - (EQB + 32)) * 256 + threadIdx.x;
        if (n < N_NODES) {
            float dinv = rsqrtf((float)(deg[n] + 1));
            float2 q; q.x = dinv * x[n]; q.y = dinv;
            q1[n] = q;                       // coalesced 8B store
        }
    }
}

// E3: edges pass 2, 4 edges/thread — 8 independent 8B gathers + 4 atomics.
// q2[s] = dinv_s^2 * (A[s] + dinv_s*x[s]) = q.y * q.y * (ac.x + q.x).
__global__ void E3_edges2(const int* __restrict__ src, const int* __restrict__ dst,
                          const float2* __restrict__ q1, const float2* __restrict__ acc2,
                          float* __restrict__ B) {
    int t = blockIdx.x * 256 + threadIdx.x;
    if (t < EQ) {
        int4 s4 = ((const int4*)src)[t];
        int4 d4 = ((const int4*)dst)[t];
        float2 q0 = q1[s4.x], q1v = q1[s4.y], q2v = q1[s4.z], q3 = q1[s4.w];
        float2 a0 = acc2[s4.x], a1 = acc2[s4.y], a2 = acc2[s4.z], a3 = acc2[s4.w];
        unsafeAtomicAdd(&B[d4.x], q0.y  * q0.y  * (a0.x + q0.x));
        unsafeAtomicAdd(&B[d4.y], q1v.y * q1v.y * (a1.x + q1v.x));
        unsafeAtomicAdd(&B[d4.z], q2v.y * q2v.y * (a2.x + q2v.x));
        unsafeAtomicAdd(&B[d4.w], q3.y  * q3.y  * (a3.x + q3.x));
    }
}

// F: MFMA final stage. Block = 256 thr (4 waves), 2 node-tiles of 16 nodes.
// a = dinv*(B + q2[n]) with q2[n] reconstructed from q1/acc2; cnf = dinv*(C + dinv).
// Phase A: T[16 node][256 m] = leaky(a*r + cnf*ru + s) bf16 in LDS. Phase B: wave w
// owns cols [32w,32w+32): 8 ds_read_b128 A-frags x 2 preloaded B-tiles ->
// 16 mfma_f32_16x16x32_bf16. Fused log_softmax + lb2.
__global__ __launch_bounds__(256, 2) void F_final(
    const float2* __restrict__ q1, const float2* __restrict__ acc2,
    const float* __restrict__ B,
    const float* __restrict__ r, const float* __restrict__ ru,
    const float* __restrict__ s,
    const short8* __restrict__ bfrag, const float* __restrict__ lb2,
    float* __restrict__ out) {
    __shared__ unsigned short tsh[16 * T_STRIDE];   // 8448 B
    __shared__ float a_sh[16], cn_sh[16];
    __shared__ float logits[16 * 132];              // 8448 B
    int tid  = threadIdx.x;
    int lane = tid & 63;
    int wave = __builtin_amdgcn_readfirstlane(tid >> 6);   // 0..3
    int row  = lane & 15, quad = lane >> 4;

    // preload B-fragments for this wave's two 16-col tiles (reused across tiles)
    short8 bf0[8], bf1[8];
#pragma unroll
    for (int ks = 0; ks < 8; ++ks) {
        bf0[ks] = bfrag[((wave * 2 + 0) * 8 + ks) * 64 + lane];
        bf1[ks] = bfrag[((wave * 2 + 1) * 8 + ks) * 64 + lane];
    }
    float cr = r[tid], cu = ru[tid], cs = s[tid];   // m = tid, constant across tiles

    for (int it = 0; it < 2; ++it) {
        int node0 = (blockIdx.x * 2 + it) * 16;     // 1250 tiles = 625 blocks x 2, exact
        if (tid < 16) {
            int n = node0 + tid;
            float2 q  = q1[n];
            float2 ac = acc2[n];
            float dinv = q.y;
            float q2n  = dinv * dinv * (ac.x + q.x);      // dinv * agg1_full
            a_sh[tid]  = dinv * (B[n] + q2n);
            cn_sh[tid] = dinv * (ac.y + dinv);
        }
        __syncthreads();                            // (0) a_sh ready; prev tsh readers done

        // Phase A: T tile, bf16
#pragma unroll
        for (int n = 0; n < 16; ++n) {
            float t = fmaf(cn_sh[n], cu, fmaf(a_sh[n], cr, cs));
            t = fmaf(SLOPE, fminf(t, 0.f), fmaxf(t, 0.f));
            tsh[n * T_STRIDE + tid] = f2bf(t);
        }
        __syncthreads();                            // (1)

        // Phase B: MFMA — wave w owns cols [32w, 32w+32)
        f32x4 acc0 = {0.f, 0.f, 0.f, 0.f}, acc1 = {0.f, 0.f, 0.f, 0.f};
        const unsigned short* tb = &tsh[row * T_STRIDE + quad * 8];
#pragma unroll
        for (int ks = 0; ks < 8; ++ks) {
            short8 af = *(const short8*)(tb + ks * 32);   // ds_read_b128, 16B aligned
            acc0 = __builtin_amdgcn_mfma_f32_16x16x32_bf16(af, bf0[ks], acc0, 0, 0, 0);
            acc1 = __builtin_amdgcn_mfma_f32_16x16x32_bf16(af, bf1[ks], acc1, 0, 0, 0);
        }
        int colbase = wave * 32;
#pragma unroll
        for (int rg = 0; rg < 4; ++rg) {
            int rw = quad * 4 + rg;                 // D: row=(lane>>4)*4+reg, col=lane&15
            logits[rw * 132 + colbase + row]      = acc0[rg];
            logits[rw * 132 + colbase + 16 + row] = acc1[rg];
        }
        __syncthreads();                            // (2)

        // log_softmax: 16 threads per node, 8 cols each (last sub: 4 valid)
        int nd = tid >> 4, sub = tid & 15, c0 = sub * 8;
        int jend = 124 - c0; if (jend > 8) jend = 8;
        float vbuf[8];
        const float* lrow = &logits[nd * 132 + c0];
        float mx = -1e30f;
        for (int j = 0; j < jend; ++j) {
            vbuf[j] = lrow[j] + lb2[c0 + j];
            mx = fmaxf(mx, vbuf[j]);
        }
        mx = fmaxf(mx, __shfl_xor(mx, 1, 16));
        mx = fmaxf(mx, __shfl_xor(mx, 2, 16));
        mx = fmaxf(mx, __shfl_xor(mx, 4, 16));
        mx = fmaxf(mx, __shfl_xor(mx, 8, 16));
        float sm = 0.f;
        for (int j = 0; j < jend; ++j) sm += __expf(vbuf[j] - mx);
        sm += __shfl_xor(sm, 1, 16);
        sm += __shfl_xor(sm, 2, 16);
        sm += __shfl_xor(sm, 4, 16);
        sm += __shfl_xor(sm, 8, 16);
        float lz = mx + __logf(sm);
        float* orow = out + (node0 + nd) * 124 + c0;
        for (int j = 0; j < jend; ++j) orow[j] = vbuf[j] - lz;
    }
}

extern "C" void kernel_launch(void* const* d_in, const int* in_sizes, int n_in,
                              void* d_out, int out_size, void* d_ws, size_t ws_size,
                              hipStream_t stream) {
    const float* x     = (const float*)d_in[0];
    const int*   ei    = (const int*)d_in[1];
    const int*   src   = ei;
    const int*   dst   = ei + N_EDGES;
    const float* W1    = (const float*)d_in[2];
    const float* b1    = (const float*)d_in[3];
    const float* W2    = (const float*)d_in[4];
    const float* b2    = (const float*)d_in[5];
    const float* gamma = (const float*)d_in[6];
    const float* beta  = (const float*)d_in[7];
    const float* rmean = (const float*)d_in[8];
    const float* rvar  = (const float*)d_in[9];
    const float* lW1   = (const float*)d_in[10];
    const float* lb1   = (const float*)d_in[11];
    const float* lW2   = (const float*)d_in[12];
    const float* lb2   = (const float*)d_in[13];
    float* out = (float*)d_out;
    float* ws  = (float*)d_ws;

    int*    deg  = (int*)(ws + OFF_DEG);
    float*  acc2 = ws + OFF_ACC2;           // float2[20000] viewed as float*
    float*  B    = ws + OFF_B;
    float*  v    = ws + OFF_V;
    float*  u    = ws + OFF_U;
    float*  r    = ws + OFF_R;
    float*  ru   = ws + OFF_RU;
    float*  s    = ws + OFF_S;
    float2* q1   = (float2*)(ws + OFF_Q1);
    unsigned short* bfrag = (unsigned short*)(ws + OFF_BFRAG);

    // one compact memset over all atomic-accumulation targets (331 KB)
    hipMemsetAsync(ws, 0, OFF_ZEND * sizeof(float), stream);

    E1_deg_v_bf<<<EQB + 256 + 16, 256, 0, stream>>>(dst, deg, W1, b1, W2, lW2, v, u, bfrag);
    E2_edges1_rs_q1<<<EQB + 32 + 79, 256, 0, stream>>>(src, dst, deg, x, acc2, q1,
                                                       v, u, gamma, beta, rmean, rvar,
                                                       b2, lW1, lb1, r, ru, s);
    E3_edges2<<<EQB, 256, 0, stream>>>(src, dst, q1, (const float2*)acc2, B);
    F_final<<<625, 256, 0, stream>>>(q1, (const float2*)acc2, B, r, ru, s,
                                     (const short8*)bfrag, lb2, out);
}

// Round 6
// 142.083 us; speedup vs baseline: 1.1027x; 1.0563x over previous
//
#include <hip/hip_runtime.h>
#include <math.h>

#define N_NODES 20000
#define N_EDGES 160000
#define EPSB 1e-5f
#define SLOPE 0.01f

typedef __attribute__((ext_vector_type(8))) short short8;   // 8 bf16 (4 VGPRs)
typedef __attribute__((ext_vector_type(4))) float f32x4;    // MFMA C/D

// ---- workspace layout (float element offsets) ----
// memset region (91 KB — only arrays accumulated in E1/E2):
#define OFF_DEG    0        // int[20000]
#define OFF_V      20000    // float[1024]
#define OFF_U      21024    // float[1024]
#define OFF_R      22048    // float[256]
#define OFF_RU     22304    // float[256]
#define OFF_S      22560    // float[256]
#define OFF_ZEND   22816
// zeroed by E1 spare blocks (first atomics in E2/E3 — dispatch boundary orders):
#define OFF_ACC2   22816    // float2[20000]: {A = sum dinv_s*x_s, C = sum dinv_s}
#define OFF_B      62816    // float[20000]:  sum q2_s per dst (edge pass 2)
// non-zeroed:
#define OFF_Q1     82816    // float2[20000]: {dinv*x, dinv}
#define OFF_BFRAG  122816   // bf16[8 ct][8 ks][64 lane][8 j] = 32768 halves

#define T_STRIDE 264   // halves; 528 B rows keep 16B alignment for ds_read_b128
#define EQ 40000       // edge quads (160000/4)
#define EQB 157        // ceil(40000/256) blocks for edge-quad passes
// E1 sub-grids: [0,EQB) hist | [EQB,EQB+512) GEMM | +16 bfrag | +59 zero acc2+B
#define E1_GEMM0 EQB
#define E1_BF0   (EQB + 512)
#define E1_Z0    (EQB + 512 + 16)
#define E1_NB    (EQB + 512 + 16 + 59)

__device__ __forceinline__ unsigned short f2bf(float f) {
    unsigned u = __float_as_uint(f);
    return (unsigned short)((u + 0x7FFFu + ((u >> 16) & 1u)) >> 16);   // RNE
}

// E1: hist (4 edges/thread) + v,u GEMM (512 blocks, c-chunks of 16) + bfrag pack
// + zero acc2/B (59 blocks of coalesced float4 stores).
__global__ void E1_deg_v_bf(const int* __restrict__ dst, int* __restrict__ deg,
                            const float* __restrict__ W1, const float* __restrict__ b1,
                            const float* __restrict__ W2, const float* __restrict__ lW2,
                            float* __restrict__ v, float* __restrict__ u,
                            unsigned short* __restrict__ bfrag,
                            float* __restrict__ zbase) {
    int b = blockIdx.x;
    if (b < EQB) {
        int t = b * 256 + threadIdx.x;
        if (t < EQ) {
            int4 d4 = ((const int4*)dst)[t];      // one coalesced 16B load
            atomicAdd(&deg[d4.x], 1);
            atomicAdd(&deg[d4.y], 1);
            atomicAdd(&deg[d4.z], 1);
            atomicAdd(&deg[d4.w], 1);
        }
    } else if (b < E1_BF0) {
        int bb = b - E1_GEMM0;              // 0..511
        int k  = (bb & 3) * 256 + threadIdx.x;
        int c0 = (bb >> 2) * 16;            // 128 chunks of 16
        float av = 0.f, au = 0.f;
        for (int c = c0; c < c0 + 16; ++c) {
            float w = W2[c * 1024 + k];     // coalesced
            av = fmaf(W1[c], w, av);
            au = fmaf(b1[c], w, au);
        }
        unsafeAtomicAdd(&v[k], av);
        unsafeAtomicAdd(&u[k], au);
    } else if (b < E1_Z0) {
        int i = (b - E1_BF0) * 256 + threadIdx.x;    // 0..4095 = (ct,ks,lane)
        int ct = i >> 9, ks = (i >> 6) & 7, lane = i & 63;
        int n  = ct * 16 + (lane & 15);
        int kb = ks * 32 + (lane >> 4) * 8;
        union { unsigned short u8[8]; short8 v8; } pk;
#pragma unroll
        for (int j = 0; j < 8; ++j)
            pk.u8[j] = (n < 124) ? f2bf(lW2[(kb + j) * 124 + n]) : (unsigned short)0;
        ((short8*)bfrag)[i] = pk.v8;
    } else {
        int i = (b - E1_Z0) * 256 + threadIdx.x;     // 15000 float4 = 60000 floats
        if (i < 15000) ((float4*)zbase)[i] = make_float4(0.f, 0.f, 0.f, 0.f);
    }
}

// E2: blocks [0,157) edges pass 1, 4 edges/thread — 8 independent gathers in flight,
// 8 fire-and-forget adjacent-line atomics; [157,189) fold BN+Linear1 into r/ru/s;
// [189,268) q1[n] = {dinv*x, dinv}.
__global__ void E2_edges1_rs_q1(const int* __restrict__ src, const int* __restrict__ dst,
                                const int* __restrict__ deg, const float* __restrict__ x,
                                float* __restrict__ acc2, float2* __restrict__ q1,
                                const float* __restrict__ v, const float* __restrict__ u,
                                const float* __restrict__ gamma, const float* __restrict__ beta,
                                const float* __restrict__ mean, const float* __restrict__ var,
                                const float* __restrict__ b2, const float* __restrict__ lW1,
                                const float* __restrict__ lb1,
                                float* __restrict__ r, float* __restrict__ ru,
                                float* __restrict__ s) {
    int b = blockIdx.x;
    if (b < EQB) {
        int t = b * 256 + threadIdx.x;
        if (t < EQ) {
            int4 s4 = ((const int4*)src)[t];
            int4 d4 = ((const int4*)dst)[t];
            // 8 independent scattered loads (compiler issues them back-to-back)
            int   g0 = deg[s4.x], g1 = deg[s4.y], g2 = deg[s4.z], g3 = deg[s4.w];
            float x0 = x[s4.x],   x1 = x[s4.y],   x2 = x[s4.z],   x3 = x[s4.w];
            float i0 = rsqrtf((float)(g0 + 1)), i1 = rsqrtf((float)(g1 + 1));
            float i2 = rsqrtf((float)(g2 + 1)), i3 = rsqrtf((float)(g3 + 1));
            unsafeAtomicAdd(&acc2[2 * d4.x],     i0 * x0);
            unsafeAtomicAdd(&acc2[2 * d4.x + 1], i0);
            unsafeAtomicAdd(&acc2[2 * d4.y],     i1 * x1);
            unsafeAtomicAdd(&acc2[2 * d4.y + 1], i1);
            unsafeAtomicAdd(&acc2[2 * d4.z],     i2 * x2);
            unsafeAtomicAdd(&acc2[2 * d4.z + 1], i2);
            unsafeAtomicAdd(&acc2[2 * d4.w],     i3 * x3);
            unsafeAtomicAdd(&acc2[2 * d4.w + 1], i3);
        }
    } else if (b < EQB + 32) {
        int bb = b - EQB, m = threadIdx.x, k0 = bb * 32;
        float ar = 0.f, aru = 0.f, as = 0.f;
        for (int k = k0; k < k0 + 32; ++k) {
            float g = gamma[k] * rsqrtf(var[k] + EPSB);
            float w = lW1[k * 256 + m];
            ar  = fmaf(v[k] * g, w, ar);
            aru = fmaf(u[k] * g, w, aru);
            as  = fmaf(fmaf(b2[k] - mean[k], g, beta[k]), w, as);
        }
        if (bb == 0) as += lb1[m];
        unsafeAtomicAdd(&r[m], ar);
        unsafeAtomicAdd(&ru[m], aru);
        unsafeAtomicAdd(&s[m], as);
    } else {
        int n = (b - (EQB + 32)) * 256 + threadIdx.x;
        if (n < N_NODES) {
            float dinv = rsqrtf((float)(deg[n] + 1));
            float2 q; q.x = dinv * x[n]; q.y = dinv;
            q1[n] = q;                       // coalesced 8B store
        }
    }
}

// E3: edges pass 2, 4 edges/thread — 8 independent 8B gathers + 4 atomics.
// q2[s] = dinv_s^2 * (A[s] + dinv_s*x[s]) = q.y * q.y * (ac.x + q.x).
__global__ void E3_edges2(const int* __restrict__ src, const int* __restrict__ dst,
                          const float2* __restrict__ q1, const float2* __restrict__ acc2,
                          float* __restrict__ B) {
    int t = blockIdx.x * 256 + threadIdx.x;
    if (t < EQ) {
        int4 s4 = ((const int4*)src)[t];
        int4 d4 = ((const int4*)dst)[t];
        float2 q0 = q1[s4.x], q1v = q1[s4.y], q2v = q1[s4.z], q3 = q1[s4.w];
        float2 a0 = acc2[s4.x], a1 = acc2[s4.y], a2 = acc2[s4.z], a3 = acc2[s4.w];
        unsafeAtomicAdd(&B[d4.x], q0.y  * q0.y  * (a0.x + q0.x));
        unsafeAtomicAdd(&B[d4.y], q1v.y * q1v.y * (a1.x + q1v.x));
        unsafeAtomicAdd(&B[d4.z], q2v.y * q2v.y * (a2.x + q2v.x));
        unsafeAtomicAdd(&B[d4.w], q3.y  * q3.y  * (a3.x + q3.x));
    }
}

// F: MFMA final stage. Block = 256 thr (4 waves), 2 node-tiles of 16 nodes.
// a = dinv*(B + q2[n]) with q2[n] reconstructed from q1/acc2; cnf = dinv*(C + dinv).
// Phase A: T[16 node][256 m] = leaky(a*r + cnf*ru + s) bf16 in LDS. Phase B: wave w
// owns cols [32w,32w+32): 8 ds_read_b128 A-frags x 2 preloaded B-tiles ->
// 16 mfma_f32_16x16x32_bf16. Fused log_softmax + lb2.
__global__ __launch_bounds__(256, 2) void F_final(
    const float2* __restrict__ q1, const float2* __restrict__ acc2,
    const float* __restrict__ B,
    const float* __restrict__ r, const float* __restrict__ ru,
    const float* __restrict__ s,
    const short8* __restrict__ bfrag, const float* __restrict__ lb2,
    float* __restrict__ out) {
    __shared__ unsigned short tsh[16 * T_STRIDE];   // 8448 B
    __shared__ float a_sh[16], cn_sh[16];
    __shared__ float logits[16 * 132];              // 8448 B
    int tid  = threadIdx.x;
    int lane = tid & 63;
    int wave = __builtin_amdgcn_readfirstlane(tid >> 6);   // 0..3
    int row  = lane & 15, quad = lane >> 4;

    // preload B-fragments for this wave's two 16-col tiles (reused across tiles)
    short8 bf0[8], bf1[8];
#pragma unroll
    for (int ks = 0; ks < 8; ++ks) {
        bf0[ks] = bfrag[((wave * 2 + 0) * 8 + ks) * 64 + lane];
        bf1[ks] = bfrag[((wave * 2 + 1) * 8 + ks) * 64 + lane];
    }
    float cr = r[tid], cu = ru[tid], cs = s[tid];   // m = tid, constant across tiles

    for (int it = 0; it < 2; ++it) {
        int node0 = (blockIdx.x * 2 + it) * 16;     // 1250 tiles = 625 blocks x 2, exact
        if (tid < 16) {
            int n = node0 + tid;
            float2 q  = q1[n];
            float2 ac = acc2[n];
            float dinv = q.y;
            float q2n  = dinv * dinv * (ac.x + q.x);      // dinv * agg1_full
            a_sh[tid]  = dinv * (B[n] + q2n);
            cn_sh[tid] = dinv * (ac.y + dinv);
        }
        __syncthreads();                            // (0) a_sh ready; prev tsh readers done

        // Phase A: T tile, bf16
#pragma unroll
        for (int n = 0; n < 16; ++n) {
            float t = fmaf(cn_sh[n], cu, fmaf(a_sh[n], cr, cs));
            t = fmaf(SLOPE, fminf(t, 0.f), fmaxf(t, 0.f));
            tsh[n * T_STRIDE + tid] = f2bf(t);
        }
        __syncthreads();                            // (1)

        // Phase B: MFMA — wave w owns cols [32w, 32w+32)
        f32x4 acc0 = {0.f, 0.f, 0.f, 0.f}, acc1 = {0.f, 0.f, 0.f, 0.f};
        const unsigned short* tb = &tsh[row * T_STRIDE + quad * 8];
#pragma unroll
        for (int ks = 0; ks < 8; ++ks) {
            short8 af = *(const short8*)(tb + ks * 32);   // ds_read_b128, 16B aligned
            acc0 = __builtin_amdgcn_mfma_f32_16x16x32_bf16(af, bf0[ks], acc0, 0, 0, 0);
            acc1 = __builtin_amdgcn_mfma_f32_16x16x32_bf16(af, bf1[ks], acc1, 0, 0, 0);
        }
        int colbase = wave * 32;
#pragma unroll
        for (int rg = 0; rg < 4; ++rg) {
            int rw = quad * 4 + rg;                 // D: row=(lane>>4)*4+reg, col=lane&15
            logits[rw * 132 + colbase + row]      = acc0[rg];
            logits[rw * 132 + colbase + 16 + row] = acc1[rg];
        }
        __syncthreads();                            // (2)

        // log_softmax: 16 threads per node, 8 cols each (last sub: 4 valid)
        int nd = tid >> 4, sub = tid & 15, c0 = sub * 8;
        int jend = 124 - c0; if (jend > 8) jend = 8;
        float vbuf[8];
        const float* lrow = &logits[nd * 132 + c0];
        float mx = -1e30f;
        for (int j = 0; j < jend; ++j) {
            vbuf[j] = lrow[j] + lb2[c0 + j];
            mx = fmaxf(mx, vbuf[j]);
        }
        mx = fmaxf(mx, __shfl_xor(mx, 1, 16));
        mx = fmaxf(mx, __shfl_xor(mx, 2, 16));
        mx = fmaxf(mx, __shfl_xor(mx, 4, 16));
        mx = fmaxf(mx, __shfl_xor(mx, 8, 16));
        float sm = 0.f;
        for (int j = 0; j < jend; ++j) sm += __expf(vbuf[j] - mx);
        sm += __shfl_xor(sm, 1, 16);
        sm += __shfl_xor(sm, 2, 16);
        sm += __shfl_xor(sm, 4, 16);
        sm += __shfl_xor(sm, 8, 16);
        float lz = mx + __logf(sm);
        float* orow = out + (node0 + nd) * 124 + c0;
        for (int j = 0; j < jend; ++j) orow[j] = vbuf[j] - lz;
    }
}

extern "C" void kernel_launch(void* const* d_in, const int* in_sizes, int n_in,
                              void* d_out, int out_size, void* d_ws, size_t ws_size,
                              hipStream_t stream) {
    const float* x     = (const float*)d_in[0];
    const int*   ei    = (const int*)d_in[1];
    const int*   src   = ei;
    const int*   dst   = ei + N_EDGES;
    const float* W1    = (const float*)d_in[2];
    const float* b1    = (const float*)d_in[3];
    const float* W2    = (const float*)d_in[4];
    const float* b2    = (const float*)d_in[5];
    const float* gamma = (const float*)d_in[6];
    const float* beta  = (const float*)d_in[7];
    const float* rmean = (const float*)d_in[8];
    const float* rvar  = (const float*)d_in[9];
    const float* lW1   = (const float*)d_in[10];
    const float* lb1   = (const float*)d_in[11];
    const float* lW2   = (const float*)d_in[12];
    const float* lb2   = (const float*)d_in[13];
    float* out = (float*)d_out;
    float* ws  = (float*)d_ws;

    int*    deg  = (int*)(ws + OFF_DEG);
    float*  v    = ws + OFF_V;
    float*  u    = ws + OFF_U;
    float*  r    = ws + OFF_R;
    float*  ru   = ws + OFF_RU;
    float*  s    = ws + OFF_S;
    float*  acc2 = ws + OFF_ACC2;           // float2[20000] viewed as float*
    float*  B    = ws + OFF_B;
    float2* q1   = (float2*)(ws + OFF_Q1);
    unsigned short* bfrag = (unsigned short*)(ws + OFF_BFRAG);

    // compact memset: only E1/E2-accumulated arrays (91 KB); acc2+B zeroed in E1
    hipMemsetAsync(ws, 0, OFF_ZEND * sizeof(float), stream);

    E1_deg_v_bf<<<E1_NB, 256, 0, stream>>>(dst, deg, W1, b1, W2, lW2, v, u, bfrag, acc2);
    E2_edges1_rs_q1<<<EQB + 32 + 79, 256, 0, stream>>>(src, dst, deg, x, acc2, q1,
                                                       v, u, gamma, beta, rmean, rvar,
                                                       b2, lW1, lb1, r, ru, s);
    E3_edges2<<<EQB, 256, 0, stream>>>(src, dst, q1, (const float2*)acc2, B);
    F_final<<<625, 256, 0, stream>>>(q1, (const float2*)acc2, B, r, ru, s,
                                     (const short8*)bfrag, lb2, out);
}